// Round 2
// baseline (263.292 us; speedup 1.0000x reference)
//
#include <hip/hip_runtime.h>

// StepConditionalLoReFT: out = h + Rn^T (W h + b - Rn h) per step s.
// All tensors FP32 (per reference). B=8 S=50 T=77 D=1024 r=16.
// Single kernel: per block (s, 64-token tile):
//   prep: Rn = R/max(||R||,eps), M = W - Rn  -> LDS as bf16
//   GEMM1: c[tok,r] = bf16(H) M^T + b   (mfma 16x16x32 bf16, K=1024)
//   GEMM2 (transposed): delta^T = Rn^T c^T  -> lane holds 4 consecutive d
//   epilogue: out = h(fp32) + delta, float4 loads/stores

typedef __attribute__((ext_vector_type(8))) short short8;
typedef __attribute__((ext_vector_type(4))) float floatx4;

__device__ __forceinline__ short f2bf(float f) {
  unsigned u = __float_as_uint(f);
  u += 0x7fffu + ((u >> 16) & 1u);   // round-to-nearest-even
  return (short)(u >> 16);
}

#define S_ 50
#define T_ 77
#define NTOK 616   // B*T tokens per step s

__global__ __launch_bounds__(256, 2) void loreft_main(
    const float* __restrict__ hG, const float* __restrict__ RG,
    const float* __restrict__ WG, const float* __restrict__ bG,
    float* __restrict__ outG) {
  // 64 KB total LDS -> 2 blocks/CU
  __shared__ short Ml[16 * 1024];   // M[r][d] bf16; 16B-block b of row r stored at (b ^ (r&7))
  __shared__ short Rt[1024 * 16];   // Rn^T: Rt[d*16 + r] bf16, no swizzle

  const int s = blockIdx.x;
  const int tid = threadIdx.x;
  const int lane = tid & 63;
  const int wvi = tid >> 6;       // wave 0..3
  const int m16 = lane & 15;
  const int quad = lane >> 4;

  // ================= prep: wave wvi computes rows r = wvi*4 .. +3 =================
#pragma unroll
  for (int rr = 0; rr < 4; ++rr) {
    const int r = wvi * 4 + rr;
    const floatx4* Rrow = (const floatx4*)(RG + (size_t)((s * 16 + r) << 10));
    const floatx4* Wrow = (const floatx4*)(WG + (size_t)((s * 16 + r) << 10));
    floatx4 rv0 = Rrow[lane * 4 + 0];
    floatx4 rv1 = Rrow[lane * 4 + 1];
    floatx4 rv2 = Rrow[lane * 4 + 2];
    floatx4 rv3 = Rrow[lane * 4 + 3];
    float ss = 0.f;
#pragma unroll
    for (int j = 0; j < 4; ++j)
      ss += rv0[j] * rv0[j] + rv1[j] * rv1[j] + rv2[j] * rv2[j] + rv3[j] * rv3[j];
#pragma unroll
    for (int m = 1; m < 64; m <<= 1) ss += __shfl_xor(ss, m);
    const float inv = 1.0f / fmaxf(sqrtf(ss), 1e-12f);

    floatx4 wa0 = Wrow[lane * 4 + 0];
    floatx4 wa1 = Wrow[lane * 4 + 1];
    floatx4 wa2 = Wrow[lane * 4 + 2];
    floatx4 wa3 = Wrow[lane * 4 + 3];
    float rn[16];
    short8 m0, m1;
#pragma unroll
    for (int j = 0; j < 4; ++j) {
      rn[j]      = rv0[j] * inv;  m0[j]     = f2bf(wa0[j] - rn[j]);
      rn[4 + j]  = rv1[j] * inv;  m0[4 + j] = f2bf(wa1[j] - rn[4 + j]);
      rn[8 + j]  = rv2[j] * inv;  m1[j]     = f2bf(wa2[j] - rn[8 + j]);
      rn[12 + j] = rv3[j] * inv;  m1[4 + j] = f2bf(wa3[j] - rn[12 + j]);
    }
    // lane covers d = lane*16 .. +15 -> 16B blocks 2*lane, 2*lane+1
    *(short8*)(Ml + r * 1024 + (((2 * lane) ^ (r & 7)) << 3)) = m0;
    *(short8*)(Ml + r * 1024 + (((2 * lane + 1) ^ (r & 7)) << 3)) = m1;
    // transpose scatter (once per block; hidden under HBM)
#pragma unroll
    for (int jj = 0; jj < 16; ++jj)
      Rt[((lane * 16 + jj) << 4) + r] = f2bf(rn[jj]);
  }
  __syncthreads();

  // ================= GEMM1: c[tok, r] = H M^T =================
  // A-frag: lane holds h[tok=m16][k = kb*32 + quad*8 + j], fp32->bf16 in regs.
  const int tokbase = blockIdx.y * 64 + wvi * 16;
  int tokA = tokbase + m16; if (tokA > NTOK - 1) tokA = NTOK - 1;
  const int bb1 = tokA / T_;
  const int tt1 = tokA - bb1 * T_;
  const size_t rowoff = ((size_t)((bb1 * S_ + s) * T_ + tt1)) << 10;
  const float* hrow = hG + rowoff;
  const floatx4* hrow4 = (const floatx4*)hrow;
  const short* mrow = Ml + m16 * 1024;
  const int msw = m16 & 7;

  floatx4 acc = {0.f, 0.f, 0.f, 0.f};
#pragma unroll 4
  for (int kb = 0; kb < 32; ++kb) {
    floatx4 p0 = hrow4[kb * 8 + quad * 2];
    floatx4 p1 = hrow4[kb * 8 + quad * 2 + 1];
    short8 af;
#pragma unroll
    for (int j = 0; j < 4; ++j) { af[j] = f2bf(p0[j]); af[4 + j] = f2bf(p1[j]); }
    short8 bf = *(const short8*)(mrow + (((kb * 4 + quad) ^ msw) << 3));
    acc = __builtin_amdgcn_mfma_f32_16x16x32_bf16(af, bf, acc, 0, 0, 0);
  }

  // c: lane holds c[tok = quad*4 + i][r = m16]; add bias b[s][r]
  const float bias = bG[s * 16 + m16];
  float cf[4];
#pragma unroll
  for (int i = 0; i < 4; ++i) cf[i] = acc[i] + bias;

  // ========== transpose c -> B-frag of GEMM2-T via shuffles ==========
  // target lane L needs B[k=r=(L>>4)*8+j][n=tok=L&15] = c[tok][r];
  // source lane = (tok>>2)*16 + r, reg = tok&3.
  unsigned lo = ((unsigned)(unsigned short)f2bf(cf[0])) |
                (((unsigned)(unsigned short)f2bf(cf[1])) << 16);
  unsigned hi = ((unsigned)(unsigned short)f2bf(cf[2])) |
                (((unsigned)(unsigned short)f2bf(cf[3])) << 16);
  short8 bfrag;
  {
    const int srcbase = ((m16 >> 2) << 4) + ((quad & 1) << 3);
    const int regsel = m16 & 3;
#pragma unroll
    for (int j = 0; j < 8; ++j) {
      unsigned vlo = __shfl(lo, srcbase + j);
      unsigned vhi = __shfl(hi, srcbase + j);
      unsigned v32 = (regsel & 2) ? vhi : vlo;
      bfrag[j] = (short)((regsel & 1) ? (v32 >> 16) : (v32 & 0xffffu));
    }
  }
  const short8 zero8 = {0, 0, 0, 0, 0, 0, 0, 0};
  if (quad >= 2) bfrag = zero8;   // k = r in [16,32) is padding

  // ========== GEMM2-T + epilogue ==========
  // A-frag: lane needs Rn[r=quad*8+j][d = dt*16 + m16]  (quads 2/3 zero)
  // D: lane holds delta[d = dt*16 + quad*4 + i][tok = m16]  -> float4 epilogue
  float* orow = outG + rowoff;
  const bool valE = (tokbase + m16) < NTOK;
  const int q16 = (quad & 1) << 3;

#pragma unroll 4
  for (int dt = 0; dt < 64; ++dt) {
    short8 t = *(const short8*)(Rt + ((dt * 16 + m16) << 4) + q16);
    short8 ar = (quad < 2) ? t : zero8;
    floatx4 z = {0.f, 0.f, 0.f, 0.f};
    floatx4 dv = __builtin_amdgcn_mfma_f32_16x16x32_bf16(ar, bfrag, z, 0, 0, 0);
    const int d0 = dt * 16 + quad * 4;
    if (valE) {
      floatx4 hv = *(const floatx4*)(hrow + d0);
      floatx4 o;
#pragma unroll
      for (int i = 0; i < 4; ++i) o[i] = hv[i] + dv[i];
      *(floatx4*)(orow + d0) = o;
    }
  }
}

extern "C" void kernel_launch(void* const* d_in, const int* in_sizes, int n_in,
                              void* d_out, int out_size, void* d_ws, size_t ws_size,
                              hipStream_t stream) {
  const float* h = (const float*)d_in[0];
  const float* R = (const float*)d_in[1];
  const float* W = (const float*)d_in[2];
  const float* b = (const float*)d_in[3];
  dim3 grid(S_, 10);
  loreft_main<<<grid, 256, 0, stream>>>(h, R, W, b, (float*)d_out);
}